// Round 1
// baseline (9289.391 us; speedup 1.0000x reference)
//
#include <hip/hip_runtime.h>
#include <cstddef>

// Problem constants
#define BB 4
#define TT 512
#define EE 1024
#define G4 4096      // 4*EE
#define VV 32000
#define EOSI 31999
#define LOG_BOUND (-1.0005003335835335e-3f)  // log(0.999)

__device__ __forceinline__ float softplusf(float x) {
  return fmaxf(x, 0.0f) + log1pf(expf(-fabsf(x)));
}
__device__ __forceinline__ float sigmoidf(float x) {
  return 1.0f / (1.0f + expf(-x));
}

// Zero initial h/c state (ws is poisoned 0xAA before every call)
__global__ void init_state(float* h0, float* h1, float* c0, float* c1) {
  int i = blockIdx.x * 256 + threadIdx.x;   // grid covers 4096
  h0[i] = 0.f; h1[i] = 0.f; c0[i] = 0.f; c1[i] = 0.f;
}

// C[M,N] = Arows[M,K] @ Bw[N,K]^T + bias1[n] + bias2[n]
// mode 0: A row = m (A base pre-offset by caller)
// mode 1: A row = tokens[b*512 + t] with m = t*4+b   (embedding gather)
// mode 2: A row = t*4 + b + 4 with m = b*512+t       (h1 buffer -> logits layout)
// Tile 128x128, BK=16, 8x8 per thread, f32.
__global__ __launch_bounds__(256) void gemm_nt(
    const float* __restrict__ A, const float* __restrict__ Bw,
    float* __restrict__ C, int M, int N, int K,
    const float* __restrict__ bias1, const float* __restrict__ bias2,
    const int* __restrict__ tokens, int mode)
{
  __shared__ float As[16][132];   // [k][row], pad 132 to break bank conflicts
  __shared__ float Bs[16][132];
  const int tid  = threadIdx.x;
  const int bcol = blockIdx.x * 128;
  const int brow = blockIdx.y * 128;

  // global staging indices: 512 float4 per tile per matrix, 2 per thread
  const int idx0 = tid, idx1 = tid + 256;
  const int ar0 = idx0 >> 2, ak0 = (idx0 & 3) * 4;
  const int ar1 = idx1 >> 2, ak1 = (idx1 & 3) * 4;

  long arow0, arow1;
  {
    int m0 = brow + ar0, m1 = brow + ar1;
    if (mode == 1) {
      arow0 = tokens[((m0 & 3) << 9) + (m0 >> 2)];
      arow1 = tokens[((m1 & 3) << 9) + (m1 >> 2)];
    } else if (mode == 2) {
      arow0 = ((m0 & 511) << 2) + (m0 >> 9) + 4;
      arow1 = ((m1 & 511) << 2) + (m1 >> 9) + 4;
    } else {
      arow0 = m0; arow1 = m1;
    }
  }
  const long brw0 = bcol + ar0, brw1 = bcol + ar1;

  float acc[8][8];
  #pragma unroll
  for (int i = 0; i < 8; ++i)
    #pragma unroll
    for (int j = 0; j < 8; ++j) acc[i][j] = 0.f;

  const int ti = tid >> 4, tj = tid & 15;

  for (int k0 = 0; k0 < K; k0 += 16) {
    float4 a0 = *(const float4*)(A  + arow0 * (long)K + k0 + ak0);
    float4 a1 = *(const float4*)(A  + arow1 * (long)K + k0 + ak1);
    float4 b0 = *(const float4*)(Bw + brw0  * (long)K + k0 + ak0);
    float4 b1 = *(const float4*)(Bw + brw1  * (long)K + k0 + ak1);
    __syncthreads();
    As[ak0+0][ar0] = a0.x; As[ak0+1][ar0] = a0.y; As[ak0+2][ar0] = a0.z; As[ak0+3][ar0] = a0.w;
    As[ak1+0][ar1] = a1.x; As[ak1+1][ar1] = a1.y; As[ak1+2][ar1] = a1.z; As[ak1+3][ar1] = a1.w;
    Bs[ak0+0][ar0] = b0.x; Bs[ak0+1][ar0] = b0.y; Bs[ak0+2][ar0] = b0.z; Bs[ak0+3][ar0] = b0.w;
    Bs[ak1+0][ar1] = b1.x; Bs[ak1+1][ar1] = b1.y; Bs[ak1+2][ar1] = b1.z; Bs[ak1+3][ar1] = b1.w;
    __syncthreads();
    #pragma unroll
    for (int kk = 0; kk < 16; ++kk) {
      float af[8], bf[8];
      #pragma unroll
      for (int i = 0; i < 8; ++i) af[i] = As[kk][ti*8 + i];
      #pragma unroll
      for (int j = 0; j < 8; ++j) bf[j] = Bs[kk][tj*8 + j];
      #pragma unroll
      for (int i = 0; i < 8; ++i)
        #pragma unroll
        for (int j = 0; j < 8; ++j) acc[i][j] += af[i] * bf[j];
    }
  }

  float bv[8];
  #pragma unroll
  for (int jj = 0; jj < 8; ++jj) {
    int n = bcol + tj*8 + jj;
    float bb = 0.f;
    if (bias1) bb += bias1[n];
    if (bias2) bb += bias2[n];
    bv[jj] = bb;
  }
  #pragma unroll
  for (int i = 0; i < 8; ++i) {
    int m = brow + ti*8 + i;
    float* cp = C + (size_t)m * N + bcol + tj*8;
    float4 v0 = make_float4(acc[i][0]+bv[0], acc[i][1]+bv[1], acc[i][2]+bv[2], acc[i][3]+bv[3]);
    float4 v1 = make_float4(acc[i][4]+bv[4], acc[i][5]+bv[5], acc[i][6]+bv[6], acc[i][7]+bv[7]);
    *(float4*)cp = v0;
    *(float4*)(cp + 4) = v1;
  }
}

// One LSTM timestep: g = gpre + hprev @ Whh^T, gates, write hout & c.
// Grid: 128 blocks x 256 threads. Block owns 8 h-dims (x 4 gates x 4 batch).
// Thread = (rl in [0,32) rows, ks in [0,8) K-split of 128 each).
__global__ __launch_bounds__(256) void lstm_step(
    const float* __restrict__ gpre,   // (4, 4096) slice for this t: [b*4096 + gate*1024 + j]
    const float* __restrict__ Whh,    // (4096, 1024)
    const float* __restrict__ hprev,  // (4*1024)
    float* __restrict__ hout,         // (4*1024)
    float* __restrict__ cst)          // (4*1024)
{
  __shared__ float hs[4 * 1024];
  __shared__ float part[32][8][4];
  __shared__ float gv[32][4];
  const int tid = threadIdx.x;

  // stage hprev into LDS (16 KB)
  {
    const float4* hp4 = (const float4*)hprev;
    float4* hw = (float4*)hs;
    for (int i = tid; i < 1024; i += 256) hw[i] = hp4[i];
  }
  __syncthreads();

  const int rl = tid >> 3, ks = tid & 7;
  const int gate = rl >> 3, jl = rl & 7;
  const int j = blockIdx.x * 8 + jl;
  const int grow = gate * 1024 + j;
  const float4* w4 = (const float4*)(Whh + (size_t)grow * 1024);
  const float4* h4 = (const float4*)hs;

  float a0 = 0.f, a1 = 0.f, a2 = 0.f, a3 = 0.f;
  #pragma unroll 4
  for (int i = 0; i < 32; ++i) {
    int k4 = i * 8 + ks;              // interleaved so the 8 ks-threads are contiguous
    float4 w  = w4[k4];
    float4 h0 = h4[k4];
    float4 h1 = h4[256 + k4];
    float4 h2 = h4[512 + k4];
    float4 h3 = h4[768 + k4];
    a0 += w.x*h0.x + w.y*h0.y + w.z*h0.z + w.w*h0.w;
    a1 += w.x*h1.x + w.y*h1.y + w.z*h1.z + w.w*h1.w;
    a2 += w.x*h2.x + w.y*h2.y + w.z*h2.z + w.w*h2.w;
    a3 += w.x*h3.x + w.y*h3.y + w.z*h3.z + w.w*h3.w;
  }
  *(float4*)&part[rl][ks][0] = make_float4(a0, a1, a2, a3);
  __syncthreads();

  if (tid < 128) {
    int r = tid >> 2, b = tid & 3;
    float s = 0.f;
    #pragma unroll
    for (int k = 0; k < 8; ++k) s += part[r][k][b];
    int gr = (r >> 3) * 1024 + blockIdx.x * 8 + (r & 7);
    gv[r][b] = gpre[b * 4096 + gr] + s;
  }
  __syncthreads();

  if (tid < 32) {
    int jj = tid >> 2, b = tid & 3;
    float gi = gv[jj][b], gf = gv[8 + jj][b], gg = gv[16 + jj][b], go = gv[24 + jj][b];
    int o = b * 1024 + blockIdx.x * 8 + jj;
    float c = sigmoidf(gf) * cst[o] + sigmoidf(gi) * tanhf(gg);
    cst[o] = c;
    hout[o] = sigmoidf(go) * tanhf(c);
  }
}

// Per-row (b,t) stats over logits in d_out:
// rowA[m] = lse_v + lse2 - shift  (subtract constant for v < EOSI)
// rowE[m] = lprob_eos - lse2      (value for v == EOSI)
__global__ __launch_bounds__(256) void row_stats(
    const float* __restrict__ logits, float* __restrict__ rowA, float* __restrict__ rowE)
{
  const int m = blockIdx.x;
  const float* row = logits + (size_t)m * VV;
  __shared__ float red[8];
  const int tid = threadIdx.x;

  float mx = -3.0e38f;
  for (int v = tid; v < EOSI; v += 256) mx = fmaxf(mx, row[v]);
  for (int off = 32; off; off >>= 1) mx = fmaxf(mx, __shfl_down(mx, off, 64));
  if ((tid & 63) == 0) red[tid >> 6] = mx;
  __syncthreads();
  if (tid == 0) red[4] = fmaxf(fmaxf(red[0], red[1]), fmaxf(red[2], red[3]));
  __syncthreads();
  mx = red[4];

  float s = 0.f;
  for (int v = tid; v < EOSI; v += 256) s += expf(row[v] - mx);
  for (int off = 32; off; off >>= 1) s += __shfl_down(s, off, 64);
  if ((tid & 63) == 0) red[tid >> 6] = s;
  __syncthreads();

  if (tid == 0) {
    s = red[0] + red[1] + red[2] + red[3];
    float lse_v = mx + logf(s);
    float eos = row[EOSI];
    int t = m & 511;                         // m = b*512 + t
    float log_lb = (float)(t + 1) * LOG_BOUND;
    float log_eos_lb = -softplusf(eos);      // log_sigmoid(-eos)
    float log_eos_ub = -softplusf(-eos);     // log_sigmoid(eos)
    float shift = log_lb + log_eos_lb;
    float f_lb = -expm1f(log_lb);            // 1 - exp(log_lb)
    float log_lb_eos = logf(f_lb) + log_eos_lb;
    float lprob_eos = log_lb_eos + softplusf(log_eos_ub - log_lb_eos);
    // logsumexp of full row collapses: logaddexp(shift, lprob_eos)
    float aa = shift, bb = lprob_eos;
    float lse2 = fmaxf(aa, bb) + log1pf(expf(-fabsf(aa - bb)));
    rowA[m] = lse_v + lse2 - shift;
    rowE[m] = lprob_eos - lse2;
  }
}

// out[m][v] = logit - rowA[m] for v < EOSI ; rowE[m] at v == EOSI. In-place, float4.
__global__ __launch_bounds__(256) void finalize(
    float* __restrict__ out, const float* __restrict__ rowA, const float* __restrict__ rowE)
{
  const int m = blockIdx.y;
  const int v4 = blockIdx.x * 256 + threadIdx.x;   // 8000 float4 per row
  if (v4 >= 8000) return;
  float4* rp = (float4*)(out + (size_t)m * VV);
  const float A = rowA[m];
  float4 p = rp[v4];
  p.x -= A; p.y -= A; p.z -= A; p.w -= A;
  if (v4 == 7999) p.w = rowE[m];
  rp[v4] = p;
}

extern "C" void kernel_launch(void* const* d_in, const int* in_sizes, int n_in,
                              void* d_out, int out_size, void* d_ws, size_t ws_size,
                              hipStream_t stream)
{
  const int*   tokens = (const int*)  d_in[0];
  const float* emb    = (const float*)d_in[1];
  const float* Wproj  = (const float*)d_in[2];
  const float* Wih0   = (const float*)d_in[3];
  const float* Whh0   = (const float*)d_in[4];
  const float* bih0   = (const float*)d_in[5];
  const float* bhh0   = (const float*)d_in[6];
  const float* Wih1   = (const float*)d_in[7];
  const float* Whh1   = (const float*)d_in[8];
  const float* bih1   = (const float*)d_in[9];
  const float* bhh1   = (const float*)d_in[10];
  float* out = (float*)d_out;

  // workspace layout (floats): ~84 MB total
  float* ws = (float*)d_ws;
  float* g0   = ws;                    // 2048 x 4096
  float* g1   = g0 + (size_t)2048*4096;
  float* h0   = g1 + (size_t)2048*4096;   // 513 slots of (4,1024); slot 0 = zeros
  float* h1   = h0 + (size_t)513*4096;
  float* c0   = h1 + (size_t)513*4096;    // 4096
  float* c1   = c0 + 4096;
  float* rowA = c1 + 4096;                // 2048
  float* rowE = rowA + 2048;

  init_state<<<16, 256, 0, stream>>>(h0, h1, c0, c1);

  // layer 0 input gates for all (t,b): emb[tokens] @ Wih0^T + bih0 + bhh0
  gemm_nt<<<dim3(32, 16), 256, 0, stream>>>(emb, Wih0, g0, 2048, 4096, 1024,
                                            bih0, bhh0, tokens, 1);
  for (int t = 0; t < 512; ++t)
    lstm_step<<<128, 256, 0, stream>>>(g0 + (size_t)t*4*4096, Whh0,
                                       h0 + (size_t)t*4096, h0 + (size_t)(t+1)*4096, c0);

  // layer 1 input gates: h0_all @ Wih1^T + bih1 + bhh1
  gemm_nt<<<dim3(32, 16), 256, 0, stream>>>(h0 + 4096, Wih1, g1, 2048, 4096, 1024,
                                            bih1, bhh1, nullptr, 0);
  for (int t = 0; t < 512; ++t)
    lstm_step<<<128, 256, 0, stream>>>(g1 + (size_t)t*4*4096, Whh1,
                                       h1 + (size_t)t*4096, h1 + (size_t)(t+1)*4096, c1);

  // projection: logits into d_out, layout (b, t, v)
  gemm_nt<<<dim3(250, 16), 256, 0, stream>>>(h1, Wproj, out, 2048, 32000, 1024,
                                             nullptr, nullptr, nullptr, 2);

  row_stats<<<2048, 256, 0, stream>>>(out, rowA, rowE);
  finalize<<<dim3(32, 2048), 256, 0, stream>>>(out, rowA, rowE);
}